// Round 5
// baseline (145.929 us; speedup 1.0000x reference)
//
#include <hip/hip_runtime.h>
#include <math.h>

#define BATCH  2
#define NVOX   8000
#define MT     32            // queries per block
#define KT     64            // keys per tile
#define NTILES 125
#define QTILES 250
#define LOG2E  1.44269504f
#define MSTAT  32.0f         // static softmax shift (log2 domain)

typedef float  f32x16 __attribute__((ext_vector_type(16)));
typedef __bf16 bf16x8 __attribute__((ext_vector_type(8)));
typedef unsigned short u16x8 __attribute__((ext_vector_type(8)));

__device__ __forceinline__ unsigned short f2bf(float f) {
    return __builtin_bit_cast(unsigned short, (__bf16)f);
}
__device__ __forceinline__ unsigned int packbf(float lo, float hi) {
    return (unsigned int)f2bf(lo) | ((unsigned int)f2bf(hi) << 16);
}
// 2^x via v_exp_f32; s_nop covers the trans->VALU wait state.
__device__ __forceinline__ float fexp2(float x) {
    float r;
    asm("v_exp_f32 %0, %1\n\ts_nop 0" : "=v"(r) : "v"(x));
    return r;
}

// ---------------------------------------------------------------------------
// Kernel 0: convert W into MFMA A-fragment layout (bf16 hi/lo), fold log2e
// into the Q rows (so attention can use raw v_exp_f32). 1 block.
//   wfrag: hi[24*256] | lo[24*256] u16, then 80 f32 biases.
//   frag fi = (ot*4+cc)*2+h, element l31*8+j = W[ot*32+l31][cc*16+8h+j]
// ---------------------------------------------------------------------------
__global__ __launch_bounds__(256) void wprep_kernel(
    const float* __restrict__ wq, const float* __restrict__ bq,
    const float* __restrict__ wk, const float* __restrict__ bk,
    const float* __restrict__ wv, const float* __restrict__ bv,
    unsigned short* __restrict__ wfrag)
{
    const int t = threadIdx.x;
    for (int i = t; i < 6144; i += 256) {
        int fi = i >> 8, r = i & 255;
        int l31 = r >> 3, j = r & 7;
        int h = fi & 1, cc = (fi >> 1) & 3, ot = fi >> 3;
        int o = ot * 32 + l31, c = cc * 16 + 8 * h + j;
        float wv_ = 0.0f;
        if (o < 8)       wv_ = wq[o * 64 + c] * LOG2E;
        else if (o < 16) wv_ = wk[(o - 8) * 64 + c];
        else if (o < 80) wv_ = wv[(o - 16) * 64 + c];
        __bf16 hb = (__bf16)wv_;
        wfrag[i]        = __builtin_bit_cast(unsigned short, hb);
        wfrag[6144 + i] = f2bf(wv_ - (float)hb);
    }
    float* wb = (float*)(wfrag + 12288);
    if (t < 80) wb[t] = (t < 8) ? bq[t] * LOG2E : (t < 16) ? bk[t - 8] : bv[t - 16];
}

// ---------------------------------------------------------------------------
// Kernel 1: projection GEMM, no LDS, no barrier. 500 blocks x 192 thr.
//   Wave ot handles o-rows ot*32..+31 for 32 voxels. W frags direct from L2.
// ---------------------------------------------------------------------------
__global__ __launch_bounds__(192) void qkv_kernel(
    const float* __restrict__ x, const unsigned short* __restrict__ wfrag,
    unsigned short* __restrict__ qws, unsigned short* __restrict__ kws,
    unsigned short* __restrict__ vws)
{
    const int t = threadIdx.x, lane = t & 63, ot = t >> 6;
    const int l31 = lane & 31, h = lane >> 5;
    const int blk = blockIdx.x, b = blk / 250, n0 = (blk % 250) * 32;
    const int n = n0 + l31, vox = b * NVOX + n;
    const float* wb = (const float*)(wfrag + 12288);

    bf16x8 Ah[4], Al[4];
#pragma unroll
    for (int cc = 0; cc < 4; ++cc) {
        const int off = ((ot * 4 + cc) * 2 + h) * 256 + l31 * 8;
        Ah[cc] = __builtin_bit_cast(bf16x8, *(const u16x8*)(wfrag + off));
        Al[cc] = __builtin_bit_cast(bf16x8, *(const u16x8*)(wfrag + 6144 + off));
    }

    bf16x8 Bhi[4], Blo[4];
    const float* xb = x + (size_t)b * 64 * NVOX + n;
#pragma unroll
    for (int cc = 0; cc < 4; ++cc) {
        unsigned short bh[8], bl[8];
#pragma unroll
        for (int j = 0; j < 8; ++j) {
            float xf = xb[(size_t)(cc * 16 + 8 * h + j) * NVOX];
            __bf16 xh = (__bf16)xf;
            bh[j] = __builtin_bit_cast(unsigned short, xh);
            bl[j] = f2bf(xf - (float)xh);
        }
        Bhi[cc] = __builtin_bit_cast(bf16x8, *(u16x8*)bh);
        Blo[cc] = __builtin_bit_cast(bf16x8, *(u16x8*)bl);
    }

    f32x16 acc;
#pragma unroll
    for (int r = 0; r < 16; ++r) acc[r] = 0.0f;
#pragma unroll
    for (int cc = 0; cc < 4; ++cc) {
        acc = __builtin_amdgcn_mfma_f32_32x32x16_bf16(Ah[cc], Bhi[cc], acc, 0, 0, 0);
        acc = __builtin_amdgcn_mfma_f32_32x32x16_bf16(Al[cc], Bhi[cc], acc, 0, 0, 0);
        acc = __builtin_amdgcn_mfma_f32_32x32x16_bf16(Ah[cc], Blo[cc], acc, 0, 0, 0);
    }

#pragma unroll
    for (int r = 0; r < 16; ++r) {
        int o = ot * 32 + (r & 3) + 8 * (r >> 2) + 4 * h;
        if (o >= 80) continue;
        float v = acc[r] + wb[o];
        if (o < 8) {
            __bf16 hb = (__bf16)v;
            qws[(size_t)vox * 16 + o]     = __builtin_bit_cast(unsigned short, hb);
            qws[(size_t)vox * 16 + 8 + o] = f2bf(v - (float)hb);
        } else if (o < 16) {
            kws[(size_t)vox * 8 + (o - 8)] = f2bf(v);
        } else {
            vws[((size_t)b * 64 + (o - 16)) * NVOX + n] = f2bf(v);
        }
    }
}

// ---------------------------------------------------------------------------
// Kernel 2: flash attention, static-m softmax, zero main-loop barriers/LDS.
//   500 blocks x 512 thr (8 waves). Wave w owns tiles T = w+8S.
//   P transpose C-layout -> B-frag fully in-register (shfl_xor 32 + select).
// ---------------------------------------------------------------------------
__global__ __launch_bounds__(512, 4) void attn_kernel(
    const unsigned short* __restrict__ qws, const unsigned short* __restrict__ kws,
    const unsigned short* __restrict__ vws, const float* __restrict__ x,
    const float* __restrict__ gamma, float* __restrict__ out)
{
    __shared__ float smem_f[8704];          // 32KB merge + 2KB l
    float* l_sh = smem_f + 8192;            // [8][64]

    const int blk = blockIdx.x, b = blk / QTILES, m0 = (blk % QTILES) * MT;
    const int t = threadIdx.x, lane = t & 63, w = t >> 6;
    const int l31 = lane & 31, h = lane >> 5;

    // Q B-frag (log2e pre-folded): col=query l31, h=0 hi / h=1 lo
    const bf16x8 qf = __builtin_bit_cast(bf16x8,
        *(const u16x8*)(qws + (size_t)(b * NVOX + m0 + l31) * 16 + h * 8));

    const unsigned short* ksrc = kws + (size_t)b * NVOX * 8;
    const unsigned short* vb0  = vws + ((size_t)b * 64 + l31) * NVOX + 8 * h;
    const unsigned short* vb1  = vb0 + (size_t)32 * NVOX;

    f32x16 acc0, acc1, zro;
#pragma unroll
    for (int r = 0; r < 16; ++r) { acc0[r] = 0.0f; acc1[r] = 0.0f; zro[r] = 0.0f; }
    float sA = 0.0f, sB = 0.0f, sC = 0.0f, sD = 0.0f;

    bf16x8 kf0 = __builtin_bit_cast(bf16x8, *(const u16x8*)(ksrc + (size_t)(w * KT + l31) * 8));
    bf16x8 kf1 = __builtin_bit_cast(bf16x8, *(const u16x8*)(ksrc + (size_t)(w * KT + 32 + l31) * 8));

    for (int S = 0; S < 16; ++S) {
        const int T = w + 8 * S;
        if (T < NTILES) {
            const int n0 = T * KT;

            // E C-layout: col=q (l31), row=key (r&3)+8(r>>2)+4h (E1: +32)
            f32x16 E0 = __builtin_amdgcn_mfma_f32_32x32x16_bf16(kf0, qf, zro, 0, 0, 0);
            f32x16 E1 = __builtin_amdgcn_mfma_f32_32x32x16_bf16(kf1, qf, zro, 0, 0, 0);

            const int Tn = T + 8;
            if (Tn < NTILES) {
                kf0 = __builtin_bit_cast(bf16x8, *(const u16x8*)(ksrc + (size_t)(Tn * KT + l31) * 8));
                kf1 = __builtin_bit_cast(bf16x8, *(const u16x8*)(ksrc + (size_t)(Tn * KT + 32 + l31) * 8));
            }

            uint4 va0[4];
#pragma unroll
            for (int s2 = 0; s2 < 4; ++s2)
                va0[s2] = *(const uint4*)(vb0 + n0 + 16 * s2);

            // p = 2^(E-32); pack pairs (rows 2g,2g+1) -> u32 bf16x2
            unsigned int pk0[8], q0s[8];
#pragma unroll
            for (int g = 0; g < 8; ++g) {
                float pa = fexp2(E0[2 * g] - MSTAT);
                float pb = fexp2(E0[2 * g + 1] - MSTAT);
                sA += pa; sB += pb;
                pk0[g] = packbf(pa, pb);
            }
#pragma unroll
            for (int g = 0; g < 8; ++g)
                q0s[g] = (unsigned int)__shfl_xor((int)pk0[g], 32, 64);

            uint4 va1[4];
#pragma unroll
            for (int s2 = 0; s2 < 4; ++s2)
                va1[s2] = *(const uint4*)(vb1 + n0 + 16 * s2);

            unsigned int pk1[8], q1s[8];
#pragma unroll
            for (int g = 0; g < 8; ++g) {
                float pa = fexp2(E1[2 * g] - MSTAT);
                float pb = fexp2(E1[2 * g + 1] - MSTAT);
                sC += pa; sD += pb;
                pk1[g] = packbf(pa, pb);
            }
#pragma unroll
            for (int g = 0; g < 8; ++g)
                q1s[g] = (unsigned int)__shfl_xor((int)pk1[g], 32, 64);

            // Build PV B-frags: lane(l31=q,h) needs keys 16s2+8h+0..7
            uint4 pf[4];
#pragma unroll
            for (int s2 = 0; s2 < 2; ++s2) {
                const int ba = 4 * s2;
                pf[s2].x = h ? q0s[ba + 2] : pk0[ba];
                pf[s2].y = h ? q0s[ba + 3] : pk0[ba + 1];
                pf[s2].z = h ? pk0[ba + 2] : q0s[ba];
                pf[s2].w = h ? pk0[ba + 3] : q0s[ba + 1];
            }
#pragma unroll
            for (int s2 = 2; s2 < 4; ++s2) {
                const int ba = 4 * (s2 - 2);
                pf[s2].x = h ? q1s[ba + 2] : pk1[ba];
                pf[s2].y = h ? q1s[ba + 3] : pk1[ba + 1];
                pf[s2].z = h ? pk1[ba + 2] : q1s[ba];
                pf[s2].w = h ? pk1[ba + 3] : q1s[ba + 1];
            }

#pragma unroll
            for (int s2 = 0; s2 < 4; ++s2)
                acc0 = __builtin_amdgcn_mfma_f32_32x32x16_bf16(
                    __builtin_bit_cast(bf16x8, va0[s2]),
                    __builtin_bit_cast(bf16x8, pf[s2]), acc0, 0, 0, 0);
#pragma unroll
            for (int s2 = 0; s2 < 4; ++s2)
                acc1 = __builtin_amdgcn_mfma_f32_32x32x16_bf16(
                    __builtin_bit_cast(bf16x8, va1[s2]),
                    __builtin_bit_cast(bf16x8, pf[s2]), acc1, 0, 0, 0);
        }
    }

    // ---- tree merge (plain sums, static m) ----
    l_sh[w * 64 + lane] = (sA + sB) + (sC + sD);
    float* mw = smem_f;
    auto wr = [&](int srcw) {
#pragma unroll
        for (int r4 = 0; r4 < 4; ++r4) {
            *(float4*)&mw[((size_t)(srcw * 2 + 0) * 64 + lane) * 16 + 4 * r4] =
                make_float4(acc0[4*r4], acc0[4*r4+1], acc0[4*r4+2], acc0[4*r4+3]);
            *(float4*)&mw[((size_t)(srcw * 2 + 1) * 64 + lane) * 16 + 4 * r4] =
                make_float4(acc1[4*r4], acc1[4*r4+1], acc1[4*r4+2], acc1[4*r4+3]);
        }
    };
    auto rd = [&](int srcw) {
#pragma unroll
        for (int r4 = 0; r4 < 4; ++r4) {
            float4 a = *(const float4*)&mw[((size_t)(srcw * 2 + 0) * 64 + lane) * 16 + 4 * r4];
            float4 c = *(const float4*)&mw[((size_t)(srcw * 2 + 1) * 64 + lane) * 16 + 4 * r4];
            acc0[4*r4]   += a.x; acc0[4*r4+1] += a.y; acc0[4*r4+2] += a.z; acc0[4*r4+3] += a.w;
            acc1[4*r4]   += c.x; acc1[4*r4+1] += c.y; acc1[4*r4+2] += c.z; acc1[4*r4+3] += c.w;
        }
    };
    if (w >= 4) wr(w - 4);
    __syncthreads();
    if (w < 4) rd(w);
    __syncthreads();
    if (w >= 2 && w < 4) wr(w - 2);
    __syncthreads();
    if (w < 2) rd(w);
    __syncthreads();
    if (w == 1) wr(0);
    __syncthreads();
    if (w == 0) {
        rd(0);
        float l_tot = 0.0f;
#pragma unroll
        for (int ww = 0; ww < 8; ++ww)
            l_tot += l_sh[ww * 64 + l31] + l_sh[ww * 64 + 32 + l31];
        const float inv = 1.0f / l_tot;
        const float g = gamma[0];
#pragma unroll
        for (int r = 0; r < 16; ++r) {
            int c = (r & 3) + 8 * (r >> 2) + 4 * h;
            size_t i0 = ((size_t)b * 64 + c) * NVOX + m0 + l31;
            size_t i1 = ((size_t)b * 64 + c + 32) * NVOX + m0 + l31;
            out[i0] = g * (acc0[r] * inv) + x[i0];
            out[i1] = g * (acc1[r] * inv) + x[i1];
        }
    }
}

// ---------------------------------------------------------------------------
extern "C" void kernel_launch(void* const* d_in, const int* in_sizes, int n_in,
                              void* d_out, int out_size, void* d_ws, size_t ws_size,
                              hipStream_t stream) {
    const float* x     = (const float*)d_in[0];
    const float* wq    = (const float*)d_in[1];
    const float* bq    = (const float*)d_in[2];
    const float* wk    = (const float*)d_in[3];
    const float* bk    = (const float*)d_in[4];
    const float* wv    = (const float*)d_in[5];
    const float* bv    = (const float*)d_in[6];
    const float* gamma = (const float*)d_in[7];
    float* out = (float*)d_out;

    unsigned short* qws = (unsigned short*)d_ws;            // [16000][16] hi|lo (log2e-scaled)
    unsigned short* kws = qws + (size_t)BATCH * NVOX * 16;  // [16000][8]
    unsigned short* vws = kws + (size_t)BATCH * NVOX * 8;   // [2][64][8000]
    unsigned short* wfrag = vws + (size_t)BATCH * 64 * NVOX; // 24896 B

    wprep_kernel<<<1, 256, 0, stream>>>(wq, bq, wk, bk, wv, bv, wfrag);
    qkv_kernel<<<500, 192, 0, stream>>>(x, wfrag, qws, kws, vws);
    attn_kernel<<<BATCH * QTILES, 512, 0, stream>>>(qws, kws, vws, x, gamma, out);
}